// Round 1
// baseline (198.086 us; speedup 1.0000x reference)
//
#include <hip/hip_runtime.h>
#include <math.h>

// MinDistLoss: global min Euclidean distance between two point clouds per batch.
// Compute-bound fp32 VALU kernel (no fp32 MFMA on CDNA4).
// Difference form (x1-x2)^2+... for numerical safety (expanded xx+yy-2zz
// cancels catastrophically vs the 2%-relative threshold at d ~ 3e-3).

#define BLOCK 256
#define R 4              // v1 points per thread (register tile)
#define TN (BLOCK * R)   // 1024 v1 points per block
#define TM 1728          // v2 points staged in LDS (1728*4 = 6912 >= 6890, 0.3% pad)

__global__ __launch_bounds__(BLOCK) void mindist_kernel(
    const float* __restrict__ v1, const float* __restrict__ v2,
    int N, int M, int nCh, int mCh, int* __restrict__ ws) {
  __shared__ float4 sv2[TM];  // 27.6 KB -> 5 blocks/CU (LDS limit)

  const int tid = threadIdx.x;
  const int per = nCh * mCh;
  const int b  = blockIdx.x / per;
  const int t  = blockIdx.x % per;
  const int nc = t / mCh;
  const int mc = t % mCh;

  // ---- stage v2 tile into LDS (index clamp -> duplicates, min unaffected)
  const float* v2b = v2 + (size_t)b * M * 3;
  const int m0 = mc * TM;
  for (int i = tid; i < TM; i += BLOCK) {
    int m = m0 + i; if (m > M - 1) m = M - 1;
    const float* p = v2b + (size_t)m * 3;
    sv2[i] = make_float4(p[0], p[1], p[2], 0.f);
  }

  // ---- load this thread's R v1 points into registers
  const float* v1b = v1 + (size_t)b * N * 3;
  float x1[R], y1[R], z1[R];
  const int n0 = nc * TN + tid;
#pragma unroll
  for (int r = 0; r < R; ++r) {
    int n = n0 + r * BLOCK; if (n > N - 1) n = N - 1;
    const float* p = v1b + (size_t)n * 3;
    x1[r] = p[0]; y1[r] = p[1]; z1[r] = p[2];
  }
  __syncthreads();

  // ---- main loop: every lane reads the same LDS word -> broadcast (free)
  float mn[R];
#pragma unroll
  for (int r = 0; r < R; ++r) mn[r] = 3.4e38f;

#pragma unroll 2
  for (int j = 0; j < TM; ++j) {
    float4 w = sv2[j];
#pragma unroll
    for (int r = 0; r < R; ++r) {
      float dx = x1[r] - w.x;
      float dy = y1[r] - w.y;
      float dz = z1[r] - w.z;
      float s = dx * dx;
      s = fmaf(dy, dy, s);
      s = fmaf(dz, dz, s);
      mn[r] = fminf(mn[r], s);   // unroll-2 pairs fold to v_min3
    }
  }

  float m2 = fminf(fminf(mn[0], mn[1]), fminf(mn[2], mn[3]));
  // wave-level min reduction (wave = 64 lanes)
#pragma unroll
  for (int off = 32; off > 0; off >>= 1)
    m2 = fminf(m2, __shfl_down(m2, off));
  // positive floats: IEEE bits are monotone as signed int -> int atomicMin works
  if ((tid & 63) == 0)
    atomicMin(ws, __float_as_int(m2));
}

__global__ void finalize_kernel(const int* __restrict__ ws, float* __restrict__ out) {
  out[0] = sqrtf(fmaxf(__int_as_float(ws[0]), 0.f));
}

extern "C" void kernel_launch(void* const* d_in, const int* in_sizes, int n_in,
                              void* d_out, int out_size, void* d_ws, size_t ws_size,
                              hipStream_t stream) {
  const float* v1 = (const float*)d_in[0];
  const float* v2 = (const float*)d_in[1];
  const int B = 16;
  const int N = in_sizes[0] / (B * 3);
  const int M = in_sizes[1] / (B * 3);
  const int nCh = (N + TN - 1) / TN;  // 7
  const int mCh = (M + TM - 1) / TM;  // 4
  // init ws[0] to 0x7f7f7f7f (3.39e38 as float) — async memset is capture-safe
  hipMemsetAsync(d_ws, 0x7f, sizeof(int), stream);
  dim3 grid(B * nCh * mCh);  // 448 blocks
  mindist_kernel<<<grid, BLOCK, 0, stream>>>(v1, v2, N, M, nCh, mCh, (int*)d_ws);
  finalize_kernel<<<1, 1, 0, stream>>>((const int*)d_ws, (float*)d_out);
}

// Round 2
// 163.189 us; speedup vs baseline: 1.2138x; 1.2138x over previous
//
#include <hip/hip_runtime.h>
#include <math.h>

// MinDistLoss: min over all pairs of ||v1[b,n]-v2[b,m]||, fp32, B=16 N=M=6890.
// Pure VALU-bound (no fp32 MFMA on CDNA4). This version targets the PACKED
// fp32 rate (v_pk_fma_f32 etc, 157 TF) via <2 x float> ext vectors: two v2
// points per packed instruction -> ~3.5 VALU instr/pair vs 6.5 scalar.
// Difference form (x1-x2)^2 for numerics (expanded form cancels at d~3e-3).

typedef float v2f __attribute__((ext_vector_type(2)));
typedef float v4f __attribute__((ext_vector_type(4)));

#define BLOCK 128        // 2 waves/block; small blocks -> fine-grained balance
#define R 8              // v1 points per thread
#define TN (BLOCK * R)   // 1024 v1 points per block -> nCh = 7
#define MCH 16           // v2 chunks -> grid = 16*7*16 = 1792 = 7 blocks/CU exact
#define TM 432           // ceil(6890/16)=431 -> 432 (mult of 4 for b128 reads)

__global__ __launch_bounds__(BLOCK) void mindist_kernel(
    const float* __restrict__ v1, const float* __restrict__ v2,
    int N, int M, int nCh, int* __restrict__ out_bits) {
  // SoA tile so 2/4 consecutive points pack into v2f/v4f registers.
  __shared__ __align__(16) float sx[TM];
  __shared__ __align__(16) float sy[TM];
  __shared__ __align__(16) float sz[TM];
  __shared__ float red[BLOCK / 64];

  const int tid = threadIdx.x;
  const int per = nCh * MCH;
  const int b  = blockIdx.x / per;
  const int t  = blockIdx.x % per;
  const int nc = t / MCH;
  const int mc = t % MCH;

  // ---- stage v2 tile (clamped indices -> duplicates; min unaffected)
  const float* v2b = v2 + (size_t)b * M * 3;
  const int m0 = mc * TM;
  for (int i = tid; i < TM; i += BLOCK) {
    int m = m0 + i; if (m > M - 1) m = M - 1;
    const float* p = v2b + (size_t)m * 3;
    sx[i] = p[0]; sy[i] = p[1]; sz[i] = p[2];
  }

  // ---- this thread's R v1 points in registers
  const float* v1b = v1 + (size_t)b * N * 3;
  float x1[R], y1[R], z1[R];
  const int n0 = nc * TN + tid;
#pragma unroll
  for (int r = 0; r < R; ++r) {
    int n = n0 + r * BLOCK; if (n > N - 1) n = N - 1;
    const float* p = v1b + (size_t)n * 3;
    x1[r] = p[0]; y1[r] = p[1]; z1[r] = p[2];
  }
  __syncthreads();

  float mn[R];
#pragma unroll
  for (int r = 0; r < R; ++r) mn[r] = 3.4e38f;

  // ---- main loop: 4 v2 points/iter as two packed halves; LDS reads are
  // wave-broadcast (same address on all lanes) -> zero bank conflicts.
  for (int j = 0; j < TM; j += 4) {
    v4f X = *(const v4f*)(sx + j);
    v4f Y = *(const v4f*)(sy + j);
    v4f Z = *(const v4f*)(sz + j);
    v2f Xa = X.xy, Xb = X.zw;
    v2f Ya = Y.xy, Yb = Y.zw;
    v2f Za = Z.xy, Zb = Z.zw;
#pragma unroll
    for (int r = 0; r < R; ++r) {
      v2f d, sa, sb;
      d = x1[r] - Xa; sa = d * d;
      d = y1[r] - Ya; sa = __builtin_elementwise_fma(d, d, sa);
      d = z1[r] - Za; sa = __builtin_elementwise_fma(d, d, sa);
      d = x1[r] - Xb; sb = d * d;
      d = y1[r] - Yb; sb = __builtin_elementwise_fma(d, d, sb);
      d = z1[r] - Zb; sb = __builtin_elementwise_fma(d, d, sb);
      mn[r] = fminf(mn[r], fminf(sa.x, sa.y));   // folds to v_min3
      mn[r] = fminf(mn[r], fminf(sb.x, sb.y));
    }
  }

  // ---- reduce: thread -> wave -> block -> one atomic
  float m2 = mn[0];
#pragma unroll
  for (int r = 1; r < R; ++r) m2 = fminf(m2, mn[r]);
#pragma unroll
  for (int off = 32; off > 0; off >>= 1)
    m2 = fminf(m2, __shfl_down(m2, off));
  if ((tid & 63) == 0) red[tid >> 6] = m2;
  __syncthreads();
  if (tid == 0) {
    float bm = red[0];
#pragma unroll
    for (int w = 1; w < BLOCK / 64; ++w) bm = fminf(bm, red[w]);
    // min(sqrt(x)) == sqrt(min(x)): apply sqrt here, skip a finalize kernel.
    // nonneg floats: IEEE bits monotone as signed int -> int atomicMin valid.
    atomicMin(out_bits, __float_as_int(sqrtf(bm)));
  }
}

extern "C" void kernel_launch(void* const* d_in, const int* in_sizes, int n_in,
                              void* d_out, int out_size, void* d_ws, size_t ws_size,
                              hipStream_t stream) {
  const float* v1 = (const float*)d_in[0];
  const float* v2 = (const float*)d_in[1];
  const int B = 16;
  const int N = in_sizes[0] / (B * 3);
  const int M = in_sizes[1] / (B * 3);
  const int nCh = (N + TN - 1) / TN;  // 7
  // init d_out to 0x7f7f7f7f (3.39e38) — async memset is graph-capture safe
  hipMemsetAsync(d_out, 0x7f, sizeof(int), stream);
  dim3 grid(B * nCh * MCH);  // 1792 blocks = 7 per CU exactly
  mindist_kernel<<<grid, BLOCK, 0, stream>>>(v1, v2, N, M, nCh, (int*)d_out);
}

// Round 3
// 160.227 us; speedup vs baseline: 1.2363x; 1.0185x over previous
//
#include <hip/hip_runtime.h>
#include <math.h>

// MinDistLoss: min over all pairs of ||v1[b,n]-v2[b,m]||, fp32, B=16 N=M=6890.
// VALU-bound; packed fp32 (v_pk_fma_f32 etc) inner loop — measured full-rate
// on gfx950 (R2: busy time 136->82 us vs scalar). Difference form for numerics
// (expanded xx+yy-2zz cancels: abs err ~1e-6 on sq ~ 8.6e-6 -> fails 2% tol).
// R3 changes: grid 1792->4032 blocks (occupancy), explicit next-iter LDS
// prefetch (hide lgkmcnt latency behind ~450 cyc of compute).

typedef float v2f __attribute__((ext_vector_type(2)));
typedef float v4f __attribute__((ext_vector_type(4)));

#define BLOCK 128        // 2 waves/block
#define R 4              // v1 points per thread
#define TN (BLOCK * R)   // 512 -> nCh = 14
#define MCH 18           // grid = 16*14*18 = 4032 = 15.75 blocks/CU
#define TM 384           // 18*384 = 6912 >= 6890 (mult of 8 for prefetch loop)

__global__ __launch_bounds__(BLOCK) void mindist_kernel(
    const float* __restrict__ v1, const float* __restrict__ v2,
    int N, int M, int nCh, int* __restrict__ out_bits) {
  // SoA tile: consecutive points pack into v2f/v4f registers.
  __shared__ __align__(16) float sx[TM];
  __shared__ __align__(16) float sy[TM];
  __shared__ __align__(16) float sz[TM];
  __shared__ float red[BLOCK / 64];

  const int tid = threadIdx.x;
  const int per = nCh * MCH;
  const int b  = blockIdx.x / per;
  const int t  = blockIdx.x % per;
  const int nc = t / MCH;
  const int mc = t % MCH;

  // ---- stage v2 tile (clamped indices -> duplicates; min unaffected)
  const float* v2b = v2 + (size_t)b * M * 3;
  const int m0 = mc * TM;
  for (int i = tid; i < TM; i += BLOCK) {
    int m = m0 + i; if (m > M - 1) m = M - 1;
    const float* p = v2b + (size_t)m * 3;
    sx[i] = p[0]; sy[i] = p[1]; sz[i] = p[2];
  }

  // ---- this thread's R v1 points in registers
  const float* v1b = v1 + (size_t)b * N * 3;
  float x1[R], y1[R], z1[R];
  const int n0 = nc * TN + tid;
#pragma unroll
  for (int r = 0; r < R; ++r) {
    int n = n0 + r * BLOCK; if (n > N - 1) n = N - 1;
    const float* p = v1b + (size_t)n * 3;
    x1[r] = p[0]; y1[r] = p[1]; z1[r] = p[2];
  }
  __syncthreads();

  float mn[R];
#pragma unroll
  for (int r = 0; r < R; ++r) mn[r] = 3.4e38f;

  // ---- main loop: 8 v2 points/iter, software-pipelined one iteration ahead.
  // All lanes read the same LDS address -> broadcast, zero bank conflicts.
  v4f cX0 = *(const v4f*)(sx + 0), cX1 = *(const v4f*)(sx + 4);
  v4f cY0 = *(const v4f*)(sy + 0), cY1 = *(const v4f*)(sy + 4);
  v4f cZ0 = *(const v4f*)(sz + 0), cZ1 = *(const v4f*)(sz + 4);

  for (int j = 0; j < TM; j += 8) {
    // prefetch next group (wraps to 0 on last iter — harmless dead load)
    int jn = j + 8; if (jn >= TM) jn = 0;
    v4f nX0 = *(const v4f*)(sx + jn), nX1 = *(const v4f*)(sx + jn + 4);
    v4f nY0 = *(const v4f*)(sy + jn), nY1 = *(const v4f*)(sy + jn + 4);
    v4f nZ0 = *(const v4f*)(sz + jn), nZ1 = *(const v4f*)(sz + jn + 4);

    v2f Xh[4] = { cX0.xy, cX0.zw, cX1.xy, cX1.zw };
    v2f Yh[4] = { cY0.xy, cY0.zw, cY1.xy, cY1.zw };
    v2f Zh[4] = { cZ0.xy, cZ0.zw, cZ1.xy, cZ1.zw };
#pragma unroll
    for (int h = 0; h < 4; ++h) {
#pragma unroll
      for (int r = 0; r < R; ++r) {
        v2f d, s;
        d = x1[r] - Xh[h]; s = d * d;
        d = y1[r] - Yh[h]; s = __builtin_elementwise_fma(d, d, s);
        d = z1[r] - Zh[h]; s = __builtin_elementwise_fma(d, d, s);
        mn[r] = fminf(mn[r], fminf(s.x, s.y));   // folds to v_min3_f32
      }
    }
    cX0 = nX0; cX1 = nX1; cY0 = nY0; cY1 = nY1; cZ0 = nZ0; cZ1 = nZ1;
  }

  // ---- reduce: thread -> wave -> block -> one atomic
  float m2 = mn[0];
#pragma unroll
  for (int r = 1; r < R; ++r) m2 = fminf(m2, mn[r]);
#pragma unroll
  for (int off = 32; off > 0; off >>= 1)
    m2 = fminf(m2, __shfl_down(m2, off));
  if ((tid & 63) == 0) red[tid >> 6] = m2;
  __syncthreads();
  if (tid == 0) {
    float bm = red[0];
#pragma unroll
    for (int w = 1; w < BLOCK / 64; ++w) bm = fminf(bm, red[w]);
    // min(sqrt) == sqrt(min); nonneg IEEE bits monotone as signed int.
    atomicMin(out_bits, __float_as_int(sqrtf(bm)));
  }
}

extern "C" void kernel_launch(void* const* d_in, const int* in_sizes, int n_in,
                              void* d_out, int out_size, void* d_ws, size_t ws_size,
                              hipStream_t stream) {
  const float* v1 = (const float*)d_in[0];
  const float* v2 = (const float*)d_in[1];
  const int B = 16;
  const int N = in_sizes[0] / (B * 3);
  const int M = in_sizes[1] / (B * 3);
  const int nCh = (N + TN - 1) / TN;  // 14
  // init d_out to 0x7f7f7f7f (3.39e38) — async memset is graph-capture safe
  hipMemsetAsync(d_out, 0x7f, sizeof(int), stream);
  dim3 grid(B * nCh * MCH);  // 4032 blocks
  mindist_kernel<<<grid, BLOCK, 0, stream>>>(v1, v2, N, M, nCh, (int*)d_out);
}